// Round 5
// baseline (330.081 us; speedup 1.0000x reference)
//
#include <hip/hip_runtime.h>
#include <cfloat>
#include <cstdint>

#define N_NODES 50000
#define N_EDGES 600000
#define HDIM    128
#define NGRAPH  2000
#define BN_EPS  1e-5f

// ---------------- CSR build ----------------

__global__ void k_init(int* degi, int* seg_s, int* seg_e) {
    int i = blockIdx.x * 256 + threadIdx.x;
    if (i < N_NODES) degi[i] = 1;                  // self-loop
    if (i < NGRAPH) { seg_s[i] = 0x7FFFFFFF; seg_e[i] = 0; }
}

// degree count (targets) + batch segment bounds, fused
__global__ void k_count_seg(const int* __restrict__ ei, int* degi,
                            const int* __restrict__ batch, int* seg_s, int* seg_e) {
    int e = blockIdx.x * 256 + threadIdx.x;
    if (e < N_EDGES) atomicAdd(&degi[ei[N_EDGES + e]], 1);
    if (e < N_NODES) {
        int g = batch[e];
        atomicMin(&seg_s[g], e);
        atomicMax(&seg_e[g], e + 1);
    }
}

// two-level exclusive scan of degi -> ptr[0..N]; also emits dinv = rsqrt(deg)
__global__ void k_scanA(const int* __restrict__ degi, int* ptr, int* bsum, float* dinv) {
    __shared__ int t[256];
    int i = blockIdx.x * 256 + threadIdx.x;
    int v = (i < N_NODES) ? degi[i] : 0;
    if (i < N_NODES) dinv[i] = rsqrtf((float)v);
    t[threadIdx.x] = v; __syncthreads();
    for (int off = 1; off < 256; off <<= 1) {
        int a = (threadIdx.x >= off) ? t[threadIdx.x - off] : 0;
        __syncthreads();
        t[threadIdx.x] += a;
        __syncthreads();
    }
    if (i < N_NODES) ptr[i + 1] = t[threadIdx.x];   // within-chunk inclusive
    if (threadIdx.x == 255) bsum[blockIdx.x] = t[255];
}

__global__ void k_scanB(const int* __restrict__ bsum, int* boff, int nb) {
    __shared__ int t[256];
    int i = threadIdx.x;
    int v = (i < nb) ? bsum[i] : 0;
    t[i] = v; __syncthreads();
    for (int off = 1; off < 256; off <<= 1) {
        int a = (i >= off) ? t[i - off] : 0;
        __syncthreads();
        t[i] += a;
        __syncthreads();
    }
    if (i < nb) boff[i] = t[i] - v;                 // exclusive
}

__global__ void k_scanC(int* ptr, const int* __restrict__ boff, int* cursor) {
    int i = blockIdx.x * 256 + threadIdx.x;
    if (i < N_NODES) {
        int val = ptr[i + 1] + boff[blockIdx.x];
        ptr[i + 1] = val;
        if (i + 1 < N_NODES) cursor[i + 1] = val;
    }
    if (i == 0) { ptr[0] = 0; cursor[0] = 0; }
}

// packed edge meta: .x = source row, .y = bitcast norm
__global__ void k_fill(const int* __restrict__ ei, const float* __restrict__ dinv,
                       int* cursor, int2* meta) {
    int e = blockIdx.x * 256 + threadIdx.x;
    if (e < N_EDGES) {
        int r = ei[e], c = ei[N_EDGES + e];
        int pos = atomicAdd(&cursor[c], 1);
        meta[pos] = make_int2(r, __float_as_int(dinv[r] * dinv[c]));
    } else if (e < N_EDGES + N_NODES) {
        int v = e - N_EDGES;
        int pos = atomicAdd(&cursor[v], 1);
        float d = dinv[v];
        meta[pos] = make_int2(v, __float_as_int(d * d));
    }
}

// ---------------- fused GCN layer:  out = relu(BN( (S·h)·W + b ))  ----------------
// Phase 1: gather S·h, ONE pass: 8 threads/node, each thread owns 4 float4 row
// slots -> 4 gathers/edge, edge loop unroll x2 = 8 independent 16B gathers in
// flight per thread. Phase 2: 4 nodes x 4 channels register-tile GEMM with W
// from global (L1/L2-resident), fused bias+BN+ReLU epilogue.

__global__ __launch_bounds__(256) void k_layer(const float4* __restrict__ h4,
                                               const int* __restrict__ ptr,
                                               const int2* __restrict__ meta,
                                               const float4* __restrict__ W4,
                                               const float4* __restrict__ bias4,
                                               const float4* __restrict__ bng4,
                                               const float4* __restrict__ bnb4,
                                               const float4* __restrict__ bnm4,
                                               const float4* __restrict__ bnv4,
                                               float4* __restrict__ hout4) {
    __shared__ float4 Hs[32 * 32];   // [local node][k-chunk] 16 KB
    int base = blockIdx.x * 32;

    // ---- Phase 1: gather (one pass: 32 nodes x 8 threads) ----
    {
        int ln = threadIdx.x >> 3;       // 0..31 local node
        int c  = threadIdx.x & 7;        // slots c, c+8, c+16, c+24
        int v  = base + ln;
        float4 a0 = make_float4(0.f, 0.f, 0.f, 0.f);
        float4 a1 = a0, a2 = a0, a3 = a0;
        if (v < N_NODES) {
            int e0 = ptr[v], e1 = ptr[v + 1];
            int j = e0;
            for (; j + 2 <= e1; j += 2) {
                int2 mA = meta[j], mB = meta[j + 1];
                const float4* rA = h4 + (size_t)mA.x * 32 + c;
                const float4* rB = h4 + (size_t)mB.x * 32 + c;
                float4 vA0 = rA[0], vA1 = rA[8], vA2 = rA[16], vA3 = rA[24];
                float4 vB0 = rB[0], vB1 = rB[8], vB2 = rB[16], vB3 = rB[24];
                float nA = __int_as_float(mA.y), nB = __int_as_float(mB.y);
                a0.x += nA * vA0.x + nB * vB0.x; a0.y += nA * vA0.y + nB * vB0.y;
                a0.z += nA * vA0.z + nB * vB0.z; a0.w += nA * vA0.w + nB * vB0.w;
                a1.x += nA * vA1.x + nB * vB1.x; a1.y += nA * vA1.y + nB * vB1.y;
                a1.z += nA * vA1.z + nB * vB1.z; a1.w += nA * vA1.w + nB * vB1.w;
                a2.x += nA * vA2.x + nB * vB2.x; a2.y += nA * vA2.y + nB * vB2.y;
                a2.z += nA * vA2.z + nB * vB2.z; a2.w += nA * vA2.w + nB * vB2.w;
                a3.x += nA * vA3.x + nB * vB3.x; a3.y += nA * vA3.y + nB * vB3.y;
                a3.z += nA * vA3.z + nB * vB3.z; a3.w += nA * vA3.w + nB * vB3.w;
            }
            if (j < e1) {                // tail: exactly one edge
                int2 mA = meta[j];
                const float4* rA = h4 + (size_t)mA.x * 32 + c;
                float4 vA0 = rA[0], vA1 = rA[8], vA2 = rA[16], vA3 = rA[24];
                float nA = __int_as_float(mA.y);
                a0.x += nA * vA0.x; a0.y += nA * vA0.y; a0.z += nA * vA0.z; a0.w += nA * vA0.w;
                a1.x += nA * vA1.x; a1.y += nA * vA1.y; a1.z += nA * vA1.z; a1.w += nA * vA1.w;
                a2.x += nA * vA2.x; a2.y += nA * vA2.y; a2.z += nA * vA2.z; a2.w += nA * vA2.w;
                a3.x += nA * vA3.x; a3.y += nA * vA3.y; a3.z += nA * vA3.z; a3.w += nA * vA3.w;
            }
        }
        Hs[ln * 32 + c +  0] = a0;
        Hs[ln * 32 + c +  8] = a1;
        Hs[ln * 32 + c + 16] = a2;
        Hs[ln * 32 + c + 24] = a3;
    }
    __syncthreads();

    // ---- Phase 2: Hs(32x128) @ W(128x128), 4 nodes x 4 channels per thread ----
    int ct = threadIdx.x & 31;       // channel group: channels 4ct..4ct+3
    int nt = threadIdx.x >> 5;       // node group: local nodes 4nt..4nt+3

    float4 acc0 = make_float4(0.f, 0.f, 0.f, 0.f);
    float4 acc1 = acc0, acc2 = acc0, acc3 = acc0;

#pragma unroll 4
    for (int kc = 0; kc < 32; kc++) {
        float4 ha = Hs[(nt * 4 + 0) * 32 + kc];
        float4 hb = Hs[(nt * 4 + 1) * 32 + kc];
        float4 hc = Hs[(nt * 4 + 2) * 32 + kc];
        float4 hd = Hs[(nt * 4 + 3) * 32 + kc];
        float4 w0 = W4[(kc * 4 + 0) * 32 + ct];
        float4 w1 = W4[(kc * 4 + 1) * 32 + ct];
        float4 w2 = W4[(kc * 4 + 2) * 32 + ct];
        float4 w3 = W4[(kc * 4 + 3) * 32 + ct];

        acc0.x += ha.x * w0.x + ha.y * w1.x + ha.z * w2.x + ha.w * w3.x;
        acc0.y += ha.x * w0.y + ha.y * w1.y + ha.z * w2.y + ha.w * w3.y;
        acc0.z += ha.x * w0.z + ha.y * w1.z + ha.z * w2.z + ha.w * w3.z;
        acc0.w += ha.x * w0.w + ha.y * w1.w + ha.z * w2.w + ha.w * w3.w;

        acc1.x += hb.x * w0.x + hb.y * w1.x + hb.z * w2.x + hb.w * w3.x;
        acc1.y += hb.x * w0.y + hb.y * w1.y + hb.z * w2.y + hb.w * w3.y;
        acc1.z += hb.x * w0.z + hb.y * w1.z + hb.z * w2.z + hb.w * w3.z;
        acc1.w += hb.x * w0.w + hb.y * w1.w + hb.z * w2.w + hb.w * w3.w;

        acc2.x += hc.x * w0.x + hc.y * w1.x + hc.z * w2.x + hc.w * w3.x;
        acc2.y += hc.x * w0.y + hc.y * w1.y + hc.z * w2.y + hc.w * w3.y;
        acc2.z += hc.x * w0.z + hc.y * w1.z + hc.z * w2.z + hc.w * w3.z;
        acc2.w += hc.x * w0.w + hc.y * w1.w + hc.z * w2.w + hc.w * w3.w;

        acc3.x += hd.x * w0.x + hd.y * w1.x + hd.z * w2.x + hd.w * w3.x;
        acc3.y += hd.x * w0.y + hd.y * w1.y + hd.z * w2.y + hd.w * w3.y;
        acc3.z += hd.x * w0.z + hd.y * w1.z + hd.z * w2.z + hd.w * w3.z;
        acc3.w += hd.x * w0.w + hd.y * w1.w + hd.z * w2.w + hd.w * w3.w;
    }

    // fused epilogue: + bias, BN (eval), ReLU
    float4 bs = bias4[ct], g = bng4[ct], bb = bnb4[ct], m = bnm4[ct], vv = bnv4[ct];
    float sx = g.x * rsqrtf(vv.x + BN_EPS), tx = bb.x - m.x * sx;
    float sy = g.y * rsqrtf(vv.y + BN_EPS), ty = bb.y - m.y * sy;
    float sz = g.z * rsqrtf(vv.z + BN_EPS), tz = bb.z - m.z * sz;
    float sw = g.w * rsqrtf(vv.w + BN_EPS), tw = bb.w - m.w * sw;

    int n0 = base + nt * 4;
    float4 accs[4] = {acc0, acc1, acc2, acc3};
#pragma unroll
    for (int q = 0; q < 4; q++) {
        int nidx = n0 + q;
        if (nidx < N_NODES) {
            float4 a = accs[q], r;
            r.x = fmaxf((a.x + bs.x) * sx + tx, 0.f);
            r.y = fmaxf((a.y + bs.y) * sy + ty, 0.f);
            r.z = fmaxf((a.z + bs.z) * sz + tz, 0.f);
            r.w = fmaxf((a.w + bs.w) * sw + tw, 0.f);
            hout4[(size_t)nidx * 32 + ct] = r;
        }
    }
}

// ---------------- pool (mean|max|sum) + MLP ----------------

__global__ __launch_bounds__(128) void k_pool(const float* __restrict__ h,
                                              const int* __restrict__ seg_s,
                                              const int* __restrict__ seg_e,
                                              const float* __restrict__ l1W,
                                              const float* __restrict__ l1b,
                                              const float* __restrict__ l2W,
                                              const float* __restrict__ l2b,
                                              float* __restrict__ out) {
    __shared__ float z[3 * HDIM];
    __shared__ float red[2];
    int g = blockIdx.x, c = threadIdx.x;
    int s = seg_s[g], e = seg_e[g];
    float sum = 0.f, mx = -FLT_MAX;
    for (int i = s; i < e; i++) {
        float val = h[(size_t)i * HDIM + c];
        sum += val;
        mx = fmaxf(mx, val);
    }
    int cnt = (s < e) ? (e - s) : 0;
    if (cnt == 0) { mx = 0.f; sum = 0.f; }
    float mean = sum / (float)(cnt > 1 ? cnt : 1);
    z[c] = mean; z[HDIM + c] = mx; z[2 * HDIM + c] = sum;
    __syncthreads();
    // MLP: unroll k by 4, float4 z reads, 4 independent l1W loads in flight
    const float4* z4 = (const float4*)z;
    float o = l1b[c];
#pragma unroll 4
    for (int k4 = 0; k4 < 96; k4++) {
        float4 zz = z4[k4];
        float w0 = l1W[(k4 * 4 + 0) * HDIM + c];
        float w1 = l1W[(k4 * 4 + 1) * HDIM + c];
        float w2 = l1W[(k4 * 4 + 2) * HDIM + c];
        float w3 = l1W[(k4 * 4 + 3) * HDIM + c];
        o += zz.x * w0 + zz.y * w1 + zz.z * w2 + zz.w * w3;
    }
    o = fmaxf(o, 0.f);
    float p = o * l2W[c];
#pragma unroll
    for (int off = 32; off; off >>= 1) p += __shfl_down(p, off, 64);
    if ((c & 63) == 0) red[c >> 6] = p;
    __syncthreads();
    if (c == 0) out[g] = red[0] + red[1] + l2b[0];
}

// ---------------- launch ----------------

extern "C" void kernel_launch(void* const* d_in, const int* in_sizes, int n_in,
                              void* d_out, int out_size, void* d_ws, size_t ws_size,
                              hipStream_t stream) {
    const float* x   = (const float*)d_in[0];
    const int*   ei  = (const int*)d_in[1];
    const int*   bat = (const int*)d_in[2];
    const float* W1  = (const float*)d_in[3];
    const float* b1  = (const float*)d_in[4];
    const float* W2  = (const float*)d_in[5];
    const float* b2  = (const float*)d_in[6];
    const float* W3  = (const float*)d_in[7];
    const float* b3  = (const float*)d_in[8];
    const float* bng = (const float*)d_in[9];
    const float* bnb = (const float*)d_in[10];
    const float* bnm = (const float*)d_in[11];
    const float* bnv = (const float*)d_in[12];
    const float* l1W = (const float*)d_in[13];
    const float* l1b = (const float*)d_in[14];
    const float* l2W = (const float*)d_in[15];
    const float* l2b = (const float*)d_in[16];
    float* out = (float*)d_out;

    char* ws = (char*)d_ws;
    size_t off = 0;
    auto alloc = [&](size_t bytes) -> char* {
        char* p = ws + off;
        off = (off + bytes + 255) & ~(size_t)255;
        return p;
    };
    int*   degi   = (int*)alloc((size_t)N_NODES * 4);
    float* dinv   = (float*)alloc((size_t)N_NODES * 4);
    int*   ptr    = (int*)alloc((size_t)(N_NODES + 1) * 4);
    int*   cursor = (int*)alloc((size_t)N_NODES * 4);
    int*   bsum   = (int*)alloc(256 * 4);
    int*   boff   = (int*)alloc(256 * 4);
    int*   seg_s  = (int*)alloc((size_t)NGRAPH * 4);
    int*   seg_e  = (int*)alloc((size_t)NGRAPH * 4);
    int2*  meta   = (int2*)alloc((size_t)(N_EDGES + N_NODES) * 8);
    float* hA     = (float*)alloc((size_t)N_NODES * HDIM * 4);
    float* hB     = (float*)alloc((size_t)N_NODES * HDIM * 4);
    (void)ws_size;

    int nblk = (N_NODES + 255) / 256;  // 196

    k_init<<<nblk, 256, 0, stream>>>(degi, seg_s, seg_e);
    k_count_seg<<<(N_EDGES + 255) / 256, 256, 0, stream>>>(ei, degi, bat, seg_s, seg_e);
    k_scanA<<<nblk, 256, 0, stream>>>(degi, ptr, bsum, dinv);
    k_scanB<<<1, 256, 0, stream>>>(bsum, boff, nblk);
    k_scanC<<<nblk, 256, 0, stream>>>(ptr, boff, cursor);
    k_fill<<<(N_EDGES + N_NODES + 255) / 256, 256, 0, stream>>>(ei, dinv, cursor, meta);

    int lb = (N_NODES + 31) / 32;  // 1563

    // layer 1: x -> hA
    k_layer<<<lb, 256, 0, stream>>>((const float4*)x, ptr, meta, (const float4*)W1,
                                    (const float4*)b1,
                                    (const float4*)(bng + 0), (const float4*)(bnb + 0),
                                    (const float4*)(bnm + 0), (const float4*)(bnv + 0),
                                    (float4*)hA);
    // layer 2: hA -> hB
    k_layer<<<lb, 256, 0, stream>>>((const float4*)hA, ptr, meta, (const float4*)W2,
                                    (const float4*)b2,
                                    (const float4*)(bng + HDIM), (const float4*)(bnb + HDIM),
                                    (const float4*)(bnm + HDIM), (const float4*)(bnv + HDIM),
                                    (float4*)hB);
    // layer 3: hB -> hA
    k_layer<<<lb, 256, 0, stream>>>((const float4*)hB, ptr, meta, (const float4*)W3,
                                    (const float4*)b3,
                                    (const float4*)(bng + 2 * HDIM), (const float4*)(bnb + 2 * HDIM),
                                    (const float4*)(bnm + 2 * HDIM), (const float4*)(bnv + 2 * HDIM),
                                    (float4*)hA);

    k_pool<<<NGRAPH, 128, 0, stream>>>(hA, seg_s, seg_e, l1W, l1b, l2W, l2b, out);
}